// Round 2
// baseline (1012.582 us; speedup 1.0000x reference)
//
#include <hip/hip_runtime.h>
#include <stdint.h>

#define A_CNT 250000
#define E_CNT 60000
#define N_NODES 100000
#define M_NAMES 20000
#define T_TYPES 512
#define H_DIM 256
#define DA    128
#define K1    384
#define K2    640
#define NEG_SLOPE 0.01f
#define SENT  0xFFFFFFFFu
#define LDSZ  (128 * 32)   // one tile buffer, in ushorts

typedef float v4f __attribute__((ext_vector_type(4)));
typedef short v8s __attribute__((ext_vector_type(8)));
typedef unsigned short u16;

// order-preserving float<->u32 for atomicMax seg-max (0 encodes below all floats)
__device__ __forceinline__ unsigned enc_f(float f) {
    unsigned u = __float_as_uint(f);
    return (u & 0x80000000u) ? ~u : (u | 0x80000000u);
}
__device__ __forceinline__ float dec_f(unsigned e) {
    unsigned u = (e & 0x80000000u) ? (e & 0x7FFFFFFFu) : ~e;
    return __uint_as_float(u);
}
__device__ __forceinline__ u16 f2bf(float f) {  // RTNE fp32->bf16
    unsigned u = __float_as_uint(f);
    u += 0x7FFFu + ((u >> 16) & 1u);
    return (u16)(u >> 16);
}
__device__ __forceinline__ uint4 pack8(float4 a, float4 b) {
    union { u16 u[8]; uint4 v; } p;
    p.u[0]=f2bf(a.x); p.u[1]=f2bf(a.y); p.u[2]=f2bf(a.z); p.u[3]=f2bf(a.w);
    p.u[4]=f2bf(b.x); p.u[5]=f2bf(b.y); p.u[6]=f2bf(b.z); p.u[7]=f2bf(b.w);
    return p.v;
}

// async global->LDS, 16B per lane. LDS dest must be wave-uniform base (+lane*16 by HW).
__device__ __forceinline__ void gload16(const u16* g, u16* l) {
    __builtin_amdgcn_global_load_lds(
        (const __attribute__((address_space(1))) unsigned int*)(g),
        (__attribute__((address_space(3))) unsigned int*)(l), 16, 0, 0);
}

// ---- W [K][256] fp32 -> Wt [256][K] bf16 (transposed for B-frag b128 reads)
__global__ void wprep_kernel(const float* __restrict__ W, u16* __restrict__ Wt, int K) {
    int k = blockIdx.x, c = threadIdx.x;
    Wt[(size_t)c * K + k] = f2bf(W[(size_t)k * 256 + c]);
}

// ---- fp32 table -> bf16 table (8 elems/thread)
__global__ void tobf16_kernel(const float* __restrict__ in, u16* __restrict__ out, int n8) {
    int i = blockIdx.x * 256 + threadIdx.x;
    if (i < n8) {
        const float4* p = (const float4*)in + (size_t)2 * i;
        float4 a = p[0], b = p[1];
        ((uint4*)out)[i] = pack8(a, b);
    }
}

__global__ void hist_kernel(const int* __restrict__ arg_edge, unsigned* __restrict__ counts) {
    int i = blockIdx.x * 256 + threadIdx.x;
    if (i < A_CNT) atomicAdd(&counts[arg_edge[i]], 1u);
}

__global__ __launch_bounds__(1024) void scan_kernel(const unsigned* __restrict__ counts,
                                                    unsigned* __restrict__ cursor) {
    __shared__ unsigned sd[1024];
    const int tid = threadIdx.x;
    const int CH = (E_CNT + 1023) / 1024;  // 59
    const int base = tid * CH;
    unsigned s = 0;
    for (int i = 0; i < CH; ++i) { int idx = base + i; if (idx < E_CNT) s += counts[idx]; }
    sd[tid] = s; __syncthreads();
    for (int d = 1; d < 1024; d <<= 1) {
        unsigned v = (tid >= d) ? sd[tid - d] : 0u; __syncthreads();
        sd[tid] += v; __syncthreads();
    }
    unsigned run = sd[tid] - s;  // exclusive base
    for (int i = 0; i < CH; ++i) {
        int idx = base + i;
        if (idx < E_CNT) { cursor[idx] = run; run += counts[idx]; }
    }
}

__global__ void scatter_kernel(const int* __restrict__ arg_edge, unsigned* __restrict__ cursor,
                               unsigned* __restrict__ perm, unsigned* __restrict__ sorted_edge) {
    int i = blockIdx.x * 256 + threadIdx.x;
    if (i < A_CNT) {
        int e = arg_edge[i];
        unsigned pos = atomicAdd(&cursor[e], 1u);
        perm[pos] = (unsigned)i;
        sorted_edge[pos] = (unsigned)e;
    }
}

// ============================================================
// GEMM1: rows = [sorted args | type rows], X @ W1 + b1, leaky,
// run-compressed atomicMax seg-max into enc table (in d_out slab).
// 128x128 tile, 256 thr. bf16 tables gathered via global_load_lds(16B),
// DOUBLE-BUFFERED LDS, counted vmcnt(4) pipeline (loads stay in flight
// across barriers; never drain to 0 in the main loop).
// ============================================================
__global__ __launch_bounds__(256, 5) void gemm1_kernel(
    const u16* __restrict__ nodes_bf, const int* __restrict__ arg_node_idx,
    const u16* __restrict__ types_bf, const int* __restrict__ type_idx,
    const u16* __restrict__ names_bf, const int* __restrict__ arg_name_idx,
    const unsigned* __restrict__ perm, const unsigned* __restrict__ sorted_edge,
    const u16* __restrict__ Wt1, const float* __restrict__ b1,
    const u16* __restrict__ zbuf,
    unsigned* __restrict__ enc)
{
    __shared__ __align__(16) u16 sX[2 * LDSZ];
    __shared__ __align__(16) u16 sW[2 * LDSZ];
    const int t = threadIdx.x;
    const int lane = t & 63, wave = t >> 6;
    const int row0 = blockIdx.x * 128;
    const int col0 = blockIdx.y * 128;

    // staging geometry: call c stages LDS rows [c*64 + wave*16, +16); this lane
    // covers row rloc = c*64 + wave*16 + (lane>>2), 16B slot (lane&3).
    const int rsub = wave * 16 + (lane >> 2);
    const int slot = lane & 3;

    const u16* xs0[2]; const u16* xs1[2]; int xcls[2];
    const u16* ws[2];
    u16* xdst[2]; u16* wdst[2];
    #pragma unroll
    for (int c = 0; c < 2; ++c) {
        const int rloc = c * 64 + rsub;
        const int ss = slot ^ ((rloc >> 1) & 3);   // inverse-swizzled SOURCE slot
        const int gr = row0 + rloc;
        if (gr < A_CNT) {
            int aid = (int)perm[gr];
            xcls[c] = 0;
            xs0[c] = names_bf + (size_t)arg_name_idx[aid] * DA + ss * 8;
            xs1[c] = nodes_bf + (size_t)arg_node_idx[aid] * H_DIM + ss * 8 - DA;
        } else if (gr < A_CNT + E_CNT) {
            xcls[c] = 1;
            xs0[c] = types_bf + (size_t)type_idx[gr - A_CNT] * H_DIM + ss * 8;
            xs1[c] = zbuf;
        } else {
            xcls[c] = 2; xs0[c] = zbuf; xs1[c] = zbuf;
        }
        ws[c]   = Wt1 + (size_t)(col0 + rloc) * K1 + ss * 8;
        xdst[c] = &sX[(c * 64 + wave * 16) * 32];   // wave-uniform
        wdst[c] = &sW[(c * 64 + wave * 16) * 32];
    }

    const int wr = (wave & 1) * 64, wc = (wave >> 1) * 64;
    const int lm = lane & 15, lq = lane >> 4;

    // read offsets (ushorts), fixed across k-steps; swizzled slot on read
    int xoff[4], woff[4];
    #pragma unroll
    for (int i = 0; i < 4; ++i) {
        int ra = wr + i * 16 + lm;
        xoff[i] = ra * 32 + (lq ^ ((ra >> 1) & 3)) * 8;
        int rb = wc + i * 16 + lm;
        woff[i] = rb * 32 + (lq ^ ((rb >> 1) & 3)) * 8;
    }

    v4f acc[4][4];
    #pragma unroll
    for (int i = 0; i < 4; ++i)
        #pragma unroll
        for (int j = 0; j < 4; ++j) acc[i][j] = (v4f)0.f;

    auto stage = [&](int buf, int kc) {   // exactly 4 vmem instructions / wave
        #pragma unroll
        for (int c = 0; c < 2; ++c) {
            const u16* xsrc;
            if (xcls[c] == 0)      xsrc = ((kc < DA) ? xs0[c] : xs1[c]) + kc;
            else if (xcls[c] == 1) xsrc = (kc < H_DIM) ? (xs0[c] + kc) : zbuf;
            else                   xsrc = zbuf;
            gload16(xsrc, xdst[c] + buf * LDSZ);
            gload16(ws[c] + kc, wdst[c] + buf * LDSZ);
        }
    };

    const int nt = K1 / 32;   // 12
    stage(0, 0);
    for (int tt = 0; tt < nt; ++tt) {
        if (tt + 1 < nt) {
            stage((tt + 1) & 1, (tt + 1) * 32);
            asm volatile("s_waitcnt vmcnt(4)" ::: "memory");   // prev stage done, next in flight
        } else {
            asm volatile("s_waitcnt vmcnt(0)" ::: "memory");
        }
        __builtin_amdgcn_sched_barrier(0);
        __builtin_amdgcn_s_barrier();       // all waves: buf[tt&1] fully staged
        __builtin_amdgcn_sched_barrier(0);

        const u16* bx = &sX[(tt & 1) * LDSZ];
        const u16* bw = &sW[(tt & 1) * LDSZ];
        v8s af[4], bf[4];
        #pragma unroll
        for (int i = 0; i < 4; ++i) af[i] = *(const v8s*)&bx[xoff[i]];
        #pragma unroll
        for (int j = 0; j < 4; ++j) bf[j] = *(const v8s*)&bw[woff[j]];
        #pragma unroll
        for (int i = 0; i < 4; ++i)
            #pragma unroll
            for (int j = 0; j < 4; ++j)
                acc[i][j] = __builtin_amdgcn_mfma_f32_16x16x32_bf16(af[i], bf[j], acc[i][j], 0, 0, 0);

        __builtin_amdgcn_sched_barrier(0);
        __builtin_amdgcn_s_barrier();       // all reads of buf[tt&1] done before it is re-staged
    }

    float bb[4];
    #pragma unroll
    for (int j = 0; j < 4; ++j) bb[j] = b1[col0 + wc + j*16 + lm];

    #pragma unroll
    for (int i = 0; i < 4; ++i) {
        const int r0 = row0 + wr + i*16 + lq*4;
        unsigned seg[4];
        #pragma unroll
        for (int reg = 0; reg < 4; ++reg) {
            int g = r0 + reg;
            seg[reg] = (g < A_CNT) ? sorted_edge[g]
                     : (g < A_CNT + E_CNT ? (unsigned)(g - A_CNT) : SENT);
        }
        #pragma unroll
        for (int j = 0; j < 4; ++j) {
            const int cj = col0 + wc + j*16 + lm;
            float v[4];
            #pragma unroll
            for (int reg = 0; reg < 4; ++reg) {
                float y = acc[i][j][reg] + bb[j];
                v[reg] = (y >= 0.f) ? y : NEG_SLOPE * y;
            }
            unsigned cs = seg[0]; float m = v[0];
            #pragma unroll
            for (int reg = 1; reg < 4; ++reg) {
                if (seg[reg] == cs) { m = fmaxf(m, v[reg]); }
                else {
                    if (cs != SENT) atomicMax(&enc[(size_t)cs * H_DIM + cj], enc_f(m));
                    cs = seg[reg]; m = v[reg];
                }
            }
            if (cs != SENT) atomicMax(&enc[(size_t)cs * H_DIM + cj], enc_f(m));
        }
    }
}

// decode enc(u32) -> fp32 in place (d_out edge slab) + bf16 copy for gemm2 gather (4/thread)
__global__ void decode_kernel(unsigned* __restrict__ enc, u16* __restrict__ es_bf) {
    size_t i = (size_t)blockIdx.x * 1024 + threadIdx.x;
    const size_t n4 = (size_t)E_CNT * H_DIM / 4;
    if (i < n4) {
        uint4 e = ((const uint4*)enc)[i];
        float4 f;
        f.x = dec_f(e.x); f.y = dec_f(e.y); f.z = dec_f(e.z); f.w = dec_f(e.w);
        ((float4*)enc)[i] = f;
        union { u16 u[4]; unsigned long long v; } p;
        p.u[0]=f2bf(f.x); p.u[1]=f2bf(f.y); p.u[2]=f2bf(f.z); p.u[3]=f2bf(f.w);
        ((unsigned long long*)es_bf)[i] = p.v;
    }
}

// ============================================================
// GEMM2: rows = args (original order), X = [es(256)|name(128)|node(256)] all bf16
// ============================================================
__global__ __launch_bounds__(256, 5) void gemm2_kernel(
    const u16* __restrict__ nodes_bf, const int* __restrict__ arg_node_idx,
    const u16* __restrict__ names_bf, const int* __restrict__ arg_name_idx,
    const int* __restrict__ arg_edge, const u16* __restrict__ es_bf,
    const u16* __restrict__ Wt2, const float* __restrict__ b2,
    const u16* __restrict__ zbuf,
    float* __restrict__ out)
{
    __shared__ __align__(16) u16 sX[2 * LDSZ];
    __shared__ __align__(16) u16 sW[2 * LDSZ];
    const int t = threadIdx.x;
    const int lane = t & 63, wave = t >> 6;
    const int row0 = blockIdx.x * 128;
    const int col0 = blockIdx.y * 128;

    const int rsub = wave * 16 + (lane >> 2);
    const int slot = lane & 3;

    const u16* pe[2]; const u16* pn[2]; const u16* pd[2]; int valid[2];
    const u16* ws[2];
    u16* xdst[2]; u16* wdst[2];
    #pragma unroll
    for (int c = 0; c < 2; ++c) {
        const int rloc = c * 64 + rsub;
        const int ss = slot ^ ((rloc >> 1) & 3);
        const int gr = row0 + rloc;
        if (gr < A_CNT) {
            valid[c] = 1;
            pe[c] = es_bf   + (size_t)arg_edge[gr]      * H_DIM + ss * 8;
            pn[c] = names_bf + (size_t)arg_name_idx[gr] * DA    + ss * 8 - H_DIM;
            pd[c] = nodes_bf + (size_t)arg_node_idx[gr] * H_DIM + ss * 8 - H_DIM - DA;
        } else {
            valid[c] = 0; pe[c] = zbuf; pn[c] = zbuf; pd[c] = zbuf;
        }
        ws[c]   = Wt2 + (size_t)(col0 + rloc) * K2 + ss * 8;
        xdst[c] = &sX[(c * 64 + wave * 16) * 32];
        wdst[c] = &sW[(c * 64 + wave * 16) * 32];
    }

    const int wr = (wave & 1) * 64, wc = (wave >> 1) * 64;
    const int lm = lane & 15, lq = lane >> 4;

    int xoff[4], woff[4];
    #pragma unroll
    for (int i = 0; i < 4; ++i) {
        int ra = wr + i * 16 + lm;
        xoff[i] = ra * 32 + (lq ^ ((ra >> 1) & 3)) * 8;
        int rb = wc + i * 16 + lm;
        woff[i] = rb * 32 + (lq ^ ((rb >> 1) & 3)) * 8;
    }

    v4f acc[4][4];
    #pragma unroll
    for (int i = 0; i < 4; ++i)
        #pragma unroll
        for (int j = 0; j < 4; ++j) acc[i][j] = (v4f)0.f;

    auto stage = [&](int buf, int kc) {   // exactly 4 vmem instructions / wave
        #pragma unroll
        for (int c = 0; c < 2; ++c) {
            const u16* xsrc;
            if (valid[c]) {
                const u16* p = (kc < H_DIM) ? pe[c] : ((kc < H_DIM + DA) ? pn[c] : pd[c]);
                xsrc = p + kc;
            } else xsrc = zbuf;
            gload16(xsrc, xdst[c] + buf * LDSZ);
            gload16(ws[c] + kc, wdst[c] + buf * LDSZ);
        }
    };

    const int nt = K2 / 32;   // 20
    stage(0, 0);
    for (int tt = 0; tt < nt; ++tt) {
        if (tt + 1 < nt) {
            stage((tt + 1) & 1, (tt + 1) * 32);
            asm volatile("s_waitcnt vmcnt(4)" ::: "memory");
        } else {
            asm volatile("s_waitcnt vmcnt(0)" ::: "memory");
        }
        __builtin_amdgcn_sched_barrier(0);
        __builtin_amdgcn_s_barrier();
        __builtin_amdgcn_sched_barrier(0);

        const u16* bx = &sX[(tt & 1) * LDSZ];
        const u16* bw = &sW[(tt & 1) * LDSZ];
        v8s af[4], bf[4];
        #pragma unroll
        for (int i = 0; i < 4; ++i) af[i] = *(const v8s*)&bx[xoff[i]];
        #pragma unroll
        for (int j = 0; j < 4; ++j) bf[j] = *(const v8s*)&bw[woff[j]];
        #pragma unroll
        for (int i = 0; i < 4; ++i)
            #pragma unroll
            for (int j = 0; j < 4; ++j)
                acc[i][j] = __builtin_amdgcn_mfma_f32_16x16x32_bf16(af[i], bf[j], acc[i][j], 0, 0, 0);

        __builtin_amdgcn_sched_barrier(0);
        __builtin_amdgcn_s_barrier();
    }

    float bb[4];
    #pragma unroll
    for (int j = 0; j < 4; ++j) bb[j] = b2[col0 + wc + j*16 + lm];

    #pragma unroll
    for (int i = 0; i < 4; ++i) {
        const int r0 = row0 + wr + i*16 + lq*4;
        #pragma unroll
        for (int reg = 0; reg < 4; ++reg) {
            const int g = r0 + reg;
            if (g < A_CNT) {
                #pragma unroll
                for (int j = 0; j < 4; ++j) {
                    float y = acc[i][j][reg] + bb[j];
                    y = (y >= 0.f) ? y : NEG_SLOPE * y;
                    out[(size_t)g * H_DIM + col0 + wc + j*16 + lm] = y;
                }
            }
        }
    }
}

extern "C" void kernel_launch(void* const* d_in, const int* in_sizes, int n_in,
                              void* d_out, int out_size, void* d_ws, size_t ws_size,
                              hipStream_t stream) {
    const float* nodes        = (const float*)d_in[0];
    const int*   arg_node_idx = (const int*)  d_in[1];
    const float* types        = (const float*)d_in[2];
    const int*   type_idx     = (const int*)  d_in[3];
    const float* names        = (const float*)d_in[4];
    const int*   arg_name_idx = (const int*)  d_in[5];
    const int*   arg_edge     = (const int*)  d_in[6];
    const float* W1           = (const float*)d_in[8];
    const float* b1           = (const float*)d_in[9];
    const float* W2           = (const float*)d_in[10];
    const float* b2           = (const float*)d_in[11];

    float* out_msg = (float*)d_out;                       // [A,256] fp32
    float* out_es  = out_msg + (size_t)A_CNT * H_DIM;     // [E,256] fp32
    unsigned* enc  = (unsigned*)out_es;                   // enc table lives in output slab

    char* ws = (char*)d_ws;
    size_t off = 0;
    auto alloc = [&](size_t bytes) -> void* {
        void* p = ws + off;
        off = (off + bytes + 255) & ~(size_t)255;
        return p;
    };
    u16* Wt1          = (u16*)alloc((size_t)256 * K1 * sizeof(u16));
    u16* Wt2          = (u16*)alloc((size_t)256 * K2 * sizeof(u16));
    u16* es_bf        = (u16*)alloc((size_t)E_CNT * H_DIM * sizeof(u16));
    u16* nodes_bf     = (u16*)alloc((size_t)N_NODES * H_DIM * sizeof(u16));
    u16* names_bf     = (u16*)alloc((size_t)M_NAMES * DA * sizeof(u16));
    u16* types_bf     = (u16*)alloc((size_t)T_TYPES * H_DIM * sizeof(u16));
    u16* zbuf         = (u16*)alloc(256);
    unsigned* counts  = (unsigned*)alloc((size_t)E_CNT * sizeof(unsigned));
    unsigned* cursor  = (unsigned*)alloc((size_t)E_CNT * sizeof(unsigned));
    unsigned* perm    = (unsigned*)alloc((size_t)A_CNT * sizeof(unsigned));
    unsigned* sorted_edge = (unsigned*)alloc((size_t)A_CNT * sizeof(unsigned));

    hipMemsetAsync(counts, 0, (size_t)E_CNT * sizeof(unsigned), stream);
    hipMemsetAsync(enc, 0, (size_t)E_CNT * H_DIM * sizeof(unsigned), stream);
    hipMemsetAsync(zbuf, 0, 256, stream);

    wprep_kernel<<<K1, 256, 0, stream>>>(W1, Wt1, K1);
    wprep_kernel<<<K2, 256, 0, stream>>>(W2, Wt2, K2);
    {
        int n8 = N_NODES * H_DIM / 8;
        tobf16_kernel<<<(n8 + 255) / 256, 256, 0, stream>>>(nodes, nodes_bf, n8);
    }
    {
        int n8 = M_NAMES * DA / 8;
        tobf16_kernel<<<(n8 + 255) / 256, 256, 0, stream>>>(names, names_bf, n8);
    }
    {
        int n8 = T_TYPES * H_DIM / 8;
        tobf16_kernel<<<(n8 + 255) / 256, 256, 0, stream>>>(types, types_bf, n8);
    }
    hist_kernel<<<(A_CNT + 255) / 256, 256, 0, stream>>>(arg_edge, counts);
    scan_kernel<<<1, 1024, 0, stream>>>(counts, cursor);
    scatter_kernel<<<(A_CNT + 255) / 256, 256, 0, stream>>>(arg_edge, cursor, perm, sorted_edge);

    dim3 g1((A_CNT + E_CNT + 127) / 128, 2);
    gemm1_kernel<<<g1, 256, 0, stream>>>(nodes_bf, arg_node_idx, types_bf, type_idx,
                                         names_bf, arg_name_idx, perm, sorted_edge,
                                         Wt1, b1, zbuf, enc);
    decode_kernel<<<((E_CNT * H_DIM / 4) + 1023) / 1024, 1024, 0, stream>>>(enc, es_bf);

    dim3 g2((A_CNT + 127) / 128, 2);
    gemm2_kernel<<<g2, 256, 0, stream>>>(nodes_bf, arg_node_idx, names_bf, arg_name_idx,
                                         arg_edge, es_bf, Wt2, b2, zbuf, out_msg);
}

// Round 3
// 876.282 us; speedup vs baseline: 1.1555x; 1.1555x over previous
//
#include <hip/hip_runtime.h>
#include <stdint.h>

#define A_CNT 250000
#define E_CNT 60000
#define N_NODES 100000
#define M_NAMES 20000
#define T_TYPES 512
#define H_DIM 256
#define DA    128
#define K1    384
#define K2    640
#define NEG_SLOPE 0.01f
#define SENT  0xFFFFFFFFu
#define LDSZ  (128 * 32)   // one tile buffer, in ushorts

typedef float v4f __attribute__((ext_vector_type(4)));
typedef short v8s __attribute__((ext_vector_type(8)));
typedef unsigned short u16;

// order-preserving float<->u32 for atomicMax seg-max (0 encodes below all floats)
__device__ __forceinline__ unsigned enc_f(float f) {
    unsigned u = __float_as_uint(f);
    return (u & 0x80000000u) ? ~u : (u | 0x80000000u);
}
__device__ __forceinline__ float dec_f(unsigned e) {
    unsigned u = (e & 0x80000000u) ? (e & 0x7FFFFFFFu) : ~e;
    return __uint_as_float(u);
}
__device__ __forceinline__ u16 f2bf(float f) {  // RTNE fp32->bf16
    unsigned u = __float_as_uint(f);
    u += 0x7FFFu + ((u >> 16) & 1u);
    return (u16)(u >> 16);
}
__device__ __forceinline__ uint4 pack8(float4 a, float4 b) {
    union { u16 u[8]; uint4 v; } p;
    p.u[0]=f2bf(a.x); p.u[1]=f2bf(a.y); p.u[2]=f2bf(a.z); p.u[3]=f2bf(a.w);
    p.u[4]=f2bf(b.x); p.u[5]=f2bf(b.y); p.u[6]=f2bf(b.z); p.u[7]=f2bf(b.w);
    return p.v;
}

// async global->LDS, 16B per lane. LDS dest must be wave-uniform base (+lane*16 by HW).
__device__ __forceinline__ void gload16(const u16* g, u16* l) {
    __builtin_amdgcn_global_load_lds(
        (const __attribute__((address_space(1))) unsigned int*)(g),
        (__attribute__((address_space(3))) unsigned int*)(l), 16, 0, 0);
}

// ---- W [K][256] fp32 -> Wt [256][K] bf16 (transposed for B-frag b128 reads)
__global__ void wprep_kernel(const float* __restrict__ W, u16* __restrict__ Wt, int K) {
    int k = blockIdx.x, c = threadIdx.x;
    Wt[(size_t)c * K + k] = f2bf(W[(size_t)k * 256 + c]);
}

// ---- fp32 table -> bf16 table (8 elems/thread)
__global__ void tobf16_kernel(const float* __restrict__ in, u16* __restrict__ out, int n8) {
    int i = blockIdx.x * 256 + threadIdx.x;
    if (i < n8) {
        const float4* p = (const float4*)in + (size_t)2 * i;
        float4 a = p[0], b = p[1];
        ((uint4*)out)[i] = pack8(a, b);
    }
}

__global__ void hist_kernel(const int* __restrict__ arg_edge, unsigned* __restrict__ counts) {
    int i = blockIdx.x * 256 + threadIdx.x;
    if (i < A_CNT) atomicAdd(&counts[arg_edge[i]], 1u);
}

__global__ __launch_bounds__(1024) void scan_kernel(const unsigned* __restrict__ counts,
                                                    unsigned* __restrict__ cursor) {
    __shared__ unsigned sd[1024];
    const int tid = threadIdx.x;
    const int CH = (E_CNT + 1023) / 1024;  // 59
    const int base = tid * CH;
    unsigned s = 0;
    for (int i = 0; i < CH; ++i) { int idx = base + i; if (idx < E_CNT) s += counts[idx]; }
    sd[tid] = s; __syncthreads();
    for (int d = 1; d < 1024; d <<= 1) {
        unsigned v = (tid >= d) ? sd[tid - d] : 0u; __syncthreads();
        sd[tid] += v; __syncthreads();
    }
    unsigned run = sd[tid] - s;  // exclusive base
    for (int i = 0; i < CH; ++i) {
        int idx = base + i;
        if (idx < E_CNT) { cursor[idx] = run; run += counts[idx]; }
    }
}

__global__ void scatter_kernel(const int* __restrict__ arg_edge, unsigned* __restrict__ cursor,
                               unsigned* __restrict__ perm, unsigned* __restrict__ sorted_edge) {
    int i = blockIdx.x * 256 + threadIdx.x;
    if (i < A_CNT) {
        int e = arg_edge[i];
        unsigned pos = atomicAdd(&cursor[e], 1u);
        perm[pos] = (unsigned)i;
        sorted_edge[pos] = (unsigned)e;
    }
}

// ============================================================
// GEMM1: rows = [sorted args | type rows], X @ W1 + b1, leaky,
// run-compressed atomicMax seg-max into enc table (in d_out slab).
// 128x128 tile, 256 thr. bf16 tables gathered via global_load_lds(16B),
// DOUBLE-BUFFERED LDS, counted vmcnt(4) pipeline. launch_bounds (256,3):
// (256,5) forced VGPR<=102 -> accumulator spill -> 2x WRITE_SIZE (round-2
// regression); 68 VGPR + 64 AGPR needs the (256,3) budget.
// ============================================================
__global__ __launch_bounds__(256, 3) void gemm1_kernel(
    const u16* __restrict__ nodes_bf, const int* __restrict__ arg_node_idx,
    const u16* __restrict__ types_bf, const int* __restrict__ type_idx,
    const u16* __restrict__ names_bf, const int* __restrict__ arg_name_idx,
    const unsigned* __restrict__ perm, const unsigned* __restrict__ sorted_edge,
    const u16* __restrict__ Wt1, const float* __restrict__ b1,
    const u16* __restrict__ zbuf,
    unsigned* __restrict__ enc)
{
    __shared__ __align__(16) u16 sX[2 * LDSZ];
    __shared__ __align__(16) u16 sW[2 * LDSZ];
    const int t = threadIdx.x;
    const int lane = t & 63, wave = t >> 6;
    const int row0 = blockIdx.x * 128;
    const int col0 = blockIdx.y * 128;

    // staging geometry: call c stages LDS rows [c*64 + wave*16, +16); this lane
    // covers row rloc = c*64 + wave*16 + (lane>>2), 16B slot (lane&3).
    const int rsub = wave * 16 + (lane >> 2);
    const int slot = lane & 3;

    const u16* xs0[2]; const u16* xs1[2]; int xcls[2];
    const u16* ws[2];
    u16* xdst[2]; u16* wdst[2];
    #pragma unroll
    for (int c = 0; c < 2; ++c) {
        const int rloc = c * 64 + rsub;
        const int ss = slot ^ ((rloc >> 1) & 3);   // inverse-swizzled SOURCE slot
        const int gr = row0 + rloc;
        if (gr < A_CNT) {
            int aid = (int)perm[gr];
            xcls[c] = 0;
            xs0[c] = names_bf + (size_t)arg_name_idx[aid] * DA + ss * 8;
            xs1[c] = nodes_bf + (size_t)arg_node_idx[aid] * H_DIM + ss * 8 - DA;
        } else if (gr < A_CNT + E_CNT) {
            xcls[c] = 1;
            xs0[c] = types_bf + (size_t)type_idx[gr - A_CNT] * H_DIM + ss * 8;
            xs1[c] = zbuf;
        } else {
            xcls[c] = 2; xs0[c] = zbuf; xs1[c] = zbuf;
        }
        ws[c]   = Wt1 + (size_t)(col0 + rloc) * K1 + ss * 8;
        xdst[c] = &sX[(c * 64 + wave * 16) * 32];   // wave-uniform
        wdst[c] = &sW[(c * 64 + wave * 16) * 32];
    }

    const int wr = (wave & 1) * 64, wc = (wave >> 1) * 64;
    const int lm = lane & 15, lq = lane >> 4;

    // read offsets (ushorts), fixed across k-steps; swizzled slot on read
    int xoff[4], woff[4];
    #pragma unroll
    for (int i = 0; i < 4; ++i) {
        int ra = wr + i * 16 + lm;
        xoff[i] = ra * 32 + (lq ^ ((ra >> 1) & 3)) * 8;
        int rb = wc + i * 16 + lm;
        woff[i] = rb * 32 + (lq ^ ((rb >> 1) & 3)) * 8;
    }

    v4f acc[4][4];
    #pragma unroll
    for (int i = 0; i < 4; ++i)
        #pragma unroll
        for (int j = 0; j < 4; ++j) acc[i][j] = (v4f)0.f;

    auto stage = [&](int buf, int kc) {   // exactly 4 vmem instructions / wave
        #pragma unroll
        for (int c = 0; c < 2; ++c) {
            const u16* xsrc;
            if (xcls[c] == 0)      xsrc = ((kc < DA) ? xs0[c] : xs1[c]) + kc;
            else if (xcls[c] == 1) xsrc = (kc < H_DIM) ? (xs0[c] + kc) : zbuf;
            else                   xsrc = zbuf;
            gload16(xsrc, xdst[c] + buf * LDSZ);
            gload16(ws[c] + kc, wdst[c] + buf * LDSZ);
        }
    };

    const int nt = K1 / 32;   // 12
    stage(0, 0);
    for (int tt = 0; tt < nt; ++tt) {
        if (tt + 1 < nt) {
            stage((tt + 1) & 1, (tt + 1) * 32);
            asm volatile("s_waitcnt vmcnt(4)" ::: "memory");   // prev stage done, next in flight
        } else {
            asm volatile("s_waitcnt vmcnt(0)" ::: "memory");
        }
        __builtin_amdgcn_sched_barrier(0);
        __builtin_amdgcn_s_barrier();       // all waves: buf[tt&1] fully staged
        __builtin_amdgcn_sched_barrier(0);

        const u16* bx = &sX[(tt & 1) * LDSZ];
        const u16* bw = &sW[(tt & 1) * LDSZ];
        v8s af[4], bf[4];
        #pragma unroll
        for (int i = 0; i < 4; ++i) af[i] = *(const v8s*)&bx[xoff[i]];
        #pragma unroll
        for (int j = 0; j < 4; ++j) bf[j] = *(const v8s*)&bw[woff[j]];
        #pragma unroll
        for (int i = 0; i < 4; ++i)
            #pragma unroll
            for (int j = 0; j < 4; ++j)
                acc[i][j] = __builtin_amdgcn_mfma_f32_16x16x32_bf16(af[i], bf[j], acc[i][j], 0, 0, 0);

        __builtin_amdgcn_sched_barrier(0);
        __builtin_amdgcn_s_barrier();       // all reads of buf[tt&1] done before it is re-staged
    }

    float bb[4];
    #pragma unroll
    for (int j = 0; j < 4; ++j) bb[j] = b1[col0 + wc + j*16 + lm];

    #pragma unroll
    for (int i = 0; i < 4; ++i) {
        const int r0 = row0 + wr + i*16 + lq*4;
        unsigned seg[4];
        #pragma unroll
        for (int reg = 0; reg < 4; ++reg) {
            int g = r0 + reg;
            seg[reg] = (g < A_CNT) ? sorted_edge[g]
                     : (g < A_CNT + E_CNT ? (unsigned)(g - A_CNT) : SENT);
        }
        #pragma unroll
        for (int j = 0; j < 4; ++j) {
            const int cj = col0 + wc + j*16 + lm;
            float v[4];
            #pragma unroll
            for (int reg = 0; reg < 4; ++reg) {
                float y = acc[i][j][reg] + bb[j];
                v[reg] = (y >= 0.f) ? y : NEG_SLOPE * y;
            }
            unsigned cs = seg[0]; float m = v[0];
            #pragma unroll
            for (int reg = 1; reg < 4; ++reg) {
                if (seg[reg] == cs) { m = fmaxf(m, v[reg]); }
                else {
                    if (cs != SENT) atomicMax(&enc[(size_t)cs * H_DIM + cj], enc_f(m));
                    cs = seg[reg]; m = v[reg];
                }
            }
            if (cs != SENT) atomicMax(&enc[(size_t)cs * H_DIM + cj], enc_f(m));
        }
    }
}

// decode enc(u32) -> fp32 in place (d_out edge slab) + bf16 copy for gemm2 gather (4/thread)
__global__ void decode_kernel(unsigned* __restrict__ enc, u16* __restrict__ es_bf) {
    size_t i = (size_t)blockIdx.x * 1024 + threadIdx.x;
    const size_t n4 = (size_t)E_CNT * H_DIM / 4;
    if (i < n4) {
        uint4 e = ((const uint4*)enc)[i];
        float4 f;
        f.x = dec_f(e.x); f.y = dec_f(e.y); f.z = dec_f(e.z); f.w = dec_f(e.w);
        ((float4*)enc)[i] = f;
        union { u16 u[4]; unsigned long long v; } p;
        p.u[0]=f2bf(f.x); p.u[1]=f2bf(f.y); p.u[2]=f2bf(f.z); p.u[3]=f2bf(f.w);
        ((unsigned long long*)es_bf)[i] = p.v;
    }
}

// ============================================================
// GEMM2: rows = args (original order), X = [es(256)|name(128)|node(256)] all bf16
// ============================================================
__global__ __launch_bounds__(256, 3) void gemm2_kernel(
    const u16* __restrict__ nodes_bf, const int* __restrict__ arg_node_idx,
    const u16* __restrict__ names_bf, const int* __restrict__ arg_name_idx,
    const int* __restrict__ arg_edge, const u16* __restrict__ es_bf,
    const u16* __restrict__ Wt2, const float* __restrict__ b2,
    const u16* __restrict__ zbuf,
    float* __restrict__ out)
{
    __shared__ __align__(16) u16 sX[2 * LDSZ];
    __shared__ __align__(16) u16 sW[2 * LDSZ];
    const int t = threadIdx.x;
    const int lane = t & 63, wave = t >> 6;
    const int row0 = blockIdx.x * 128;
    const int col0 = blockIdx.y * 128;

    const int rsub = wave * 16 + (lane >> 2);
    const int slot = lane & 3;

    const u16* pe[2]; const u16* pn[2]; const u16* pd[2]; int valid[2];
    const u16* ws[2];
    u16* xdst[2]; u16* wdst[2];
    #pragma unroll
    for (int c = 0; c < 2; ++c) {
        const int rloc = c * 64 + rsub;
        const int ss = slot ^ ((rloc >> 1) & 3);
        const int gr = row0 + rloc;
        if (gr < A_CNT) {
            valid[c] = 1;
            pe[c] = es_bf   + (size_t)arg_edge[gr]      * H_DIM + ss * 8;
            pn[c] = names_bf + (size_t)arg_name_idx[gr] * DA    + ss * 8 - H_DIM;
            pd[c] = nodes_bf + (size_t)arg_node_idx[gr] * H_DIM + ss * 8 - H_DIM - DA;
        } else {
            valid[c] = 0; pe[c] = zbuf; pn[c] = zbuf; pd[c] = zbuf;
        }
        ws[c]   = Wt2 + (size_t)(col0 + rloc) * K2 + ss * 8;
        xdst[c] = &sX[(c * 64 + wave * 16) * 32];
        wdst[c] = &sW[(c * 64 + wave * 16) * 32];
    }

    const int wr = (wave & 1) * 64, wc = (wave >> 1) * 64;
    const int lm = lane & 15, lq = lane >> 4;

    int xoff[4], woff[4];
    #pragma unroll
    for (int i = 0; i < 4; ++i) {
        int ra = wr + i * 16 + lm;
        xoff[i] = ra * 32 + (lq ^ ((ra >> 1) & 3)) * 8;
        int rb = wc + i * 16 + lm;
        woff[i] = rb * 32 + (lq ^ ((rb >> 1) & 3)) * 8;
    }

    v4f acc[4][4];
    #pragma unroll
    for (int i = 0; i < 4; ++i)
        #pragma unroll
        for (int j = 0; j < 4; ++j) acc[i][j] = (v4f)0.f;

    auto stage = [&](int buf, int kc) {   // exactly 4 vmem instructions / wave
        #pragma unroll
        for (int c = 0; c < 2; ++c) {
            const u16* xsrc;
            if (valid[c]) {
                const u16* p = (kc < H_DIM) ? pe[c] : ((kc < H_DIM + DA) ? pn[c] : pd[c]);
                xsrc = p + kc;
            } else xsrc = zbuf;
            gload16(xsrc, xdst[c] + buf * LDSZ);
            gload16(ws[c] + kc, wdst[c] + buf * LDSZ);
        }
    };

    const int nt = K2 / 32;   // 20
    stage(0, 0);
    for (int tt = 0; tt < nt; ++tt) {
        if (tt + 1 < nt) {
            stage((tt + 1) & 1, (tt + 1) * 32);
            asm volatile("s_waitcnt vmcnt(4)" ::: "memory");
        } else {
            asm volatile("s_waitcnt vmcnt(0)" ::: "memory");
        }
        __builtin_amdgcn_sched_barrier(0);
        __builtin_amdgcn_s_barrier();
        __builtin_amdgcn_sched_barrier(0);

        const u16* bx = &sX[(tt & 1) * LDSZ];
        const u16* bw = &sW[(tt & 1) * LDSZ];
        v8s af[4], bf[4];
        #pragma unroll
        for (int i = 0; i < 4; ++i) af[i] = *(const v8s*)&bx[xoff[i]];
        #pragma unroll
        for (int j = 0; j < 4; ++j) bf[j] = *(const v8s*)&bw[woff[j]];
        #pragma unroll
        for (int i = 0; i < 4; ++i)
            #pragma unroll
            for (int j = 0; j < 4; ++j)
                acc[i][j] = __builtin_amdgcn_mfma_f32_16x16x32_bf16(af[i], bf[j], acc[i][j], 0, 0, 0);

        __builtin_amdgcn_sched_barrier(0);
        __builtin_amdgcn_s_barrier();
    }

    float bb[4];
    #pragma unroll
    for (int j = 0; j < 4; ++j) bb[j] = b2[col0 + wc + j*16 + lm];

    #pragma unroll
    for (int i = 0; i < 4; ++i) {
        const int r0 = row0 + wr + i*16 + lq*4;
        #pragma unroll
        for (int reg = 0; reg < 4; ++reg) {
            const int g = r0 + reg;
            if (g < A_CNT) {
                #pragma unroll
                for (int j = 0; j < 4; ++j) {
                    float y = acc[i][j][reg] + bb[j];
                    y = (y >= 0.f) ? y : NEG_SLOPE * y;
                    out[(size_t)g * H_DIM + col0 + wc + j*16 + lm] = y;
                }
            }
        }
    }
}

extern "C" void kernel_launch(void* const* d_in, const int* in_sizes, int n_in,
                              void* d_out, int out_size, void* d_ws, size_t ws_size,
                              hipStream_t stream) {
    const float* nodes        = (const float*)d_in[0];
    const int*   arg_node_idx = (const int*)  d_in[1];
    const float* types        = (const float*)d_in[2];
    const int*   type_idx     = (const int*)  d_in[3];
    const float* names        = (const float*)d_in[4];
    const int*   arg_name_idx = (const int*)  d_in[5];
    const int*   arg_edge     = (const int*)  d_in[6];
    const float* W1           = (const float*)d_in[8];
    const float* b1           = (const float*)d_in[9];
    const float* W2           = (const float*)d_in[10];
    const float* b2           = (const float*)d_in[11];

    float* out_msg = (float*)d_out;                       // [A,256] fp32
    float* out_es  = out_msg + (size_t)A_CNT * H_DIM;     // [E,256] fp32
    unsigned* enc  = (unsigned*)out_es;                   // enc table lives in output slab

    char* ws = (char*)d_ws;
    size_t off = 0;
    auto alloc = [&](size_t bytes) -> void* {
        void* p = ws + off;
        off = (off + bytes + 255) & ~(size_t)255;
        return p;
    };
    u16* Wt1          = (u16*)alloc((size_t)256 * K1 * sizeof(u16));
    u16* Wt2          = (u16*)alloc((size_t)256 * K2 * sizeof(u16));
    u16* es_bf        = (u16*)alloc((size_t)E_CNT * H_DIM * sizeof(u16));
    u16* nodes_bf     = (u16*)alloc((size_t)N_NODES * H_DIM * sizeof(u16));
    u16* names_bf     = (u16*)alloc((size_t)M_NAMES * DA * sizeof(u16));
    u16* types_bf     = (u16*)alloc((size_t)T_TYPES * H_DIM * sizeof(u16));
    u16* zbuf         = (u16*)alloc(256);
    unsigned* counts  = (unsigned*)alloc((size_t)E_CNT * sizeof(unsigned));
    unsigned* cursor  = (unsigned*)alloc((size_t)E_CNT * sizeof(unsigned));
    unsigned* perm    = (unsigned*)alloc((size_t)A_CNT * sizeof(unsigned));
    unsigned* sorted_edge = (unsigned*)alloc((size_t)A_CNT * sizeof(unsigned));

    hipMemsetAsync(counts, 0, (size_t)E_CNT * sizeof(unsigned), stream);
    hipMemsetAsync(enc, 0, (size_t)E_CNT * H_DIM * sizeof(unsigned), stream);
    hipMemsetAsync(zbuf, 0, 256, stream);

    wprep_kernel<<<K1, 256, 0, stream>>>(W1, Wt1, K1);
    wprep_kernel<<<K2, 256, 0, stream>>>(W2, Wt2, K2);
    {
        int n8 = N_NODES * H_DIM / 8;
        tobf16_kernel<<<(n8 + 255) / 256, 256, 0, stream>>>(nodes, nodes_bf, n8);
    }
    {
        int n8 = M_NAMES * DA / 8;
        tobf16_kernel<<<(n8 + 255) / 256, 256, 0, stream>>>(names, names_bf, n8);
    }
    {
        int n8 = T_TYPES * H_DIM / 8;
        tobf16_kernel<<<(n8 + 255) / 256, 256, 0, stream>>>(types, types_bf, n8);
    }
    hist_kernel<<<(A_CNT + 255) / 256, 256, 0, stream>>>(arg_edge, counts);
    scan_kernel<<<1, 1024, 0, stream>>>(counts, cursor);
    scatter_kernel<<<(A_CNT + 255) / 256, 256, 0, stream>>>(arg_edge, cursor, perm, sorted_edge);

    dim3 g1((A_CNT + E_CNT + 127) / 128, 2);
    gemm1_kernel<<<g1, 256, 0, stream>>>(nodes_bf, arg_node_idx, types_bf, type_idx,
                                         names_bf, arg_name_idx, perm, sorted_edge,
                                         Wt1, b1, zbuf, enc);
    decode_kernel<<<((E_CNT * H_DIM / 4) + 1023) / 1024, 1024, 0, stream>>>(enc, es_bf);

    dim3 g2((A_CNT + 127) / 128, 2);
    gemm2_kernel<<<g2, 256, 0, stream>>>(nodes_bf, arg_node_idx, names_bf, arg_name_idx,
                                         arg_edge, es_bf, Wt2, b2, zbuf, out_msg);
}

// Round 6
// 842.611 us; speedup vs baseline: 1.2017x; 1.0400x over previous
//
#include <hip/hip_runtime.h>
#include <stdint.h>

#define A_CNT 250000
#define E_CNT 60000
#define N_NODES 100000
#define M_NAMES 20000
#define T_TYPES 512
#define H_DIM 256
#define DA    128
#define K1    384
#define K2    640
#define NEG_SLOPE 0.01f
#define SENT  0xFFFFFFFFu
#define LDSZ  (128 * 32)   // one tile buffer, in ushorts

typedef float v4f __attribute__((ext_vector_type(4)));
typedef short v8s __attribute__((ext_vector_type(8)));
typedef unsigned short u16;

// order-preserving float<->u32 for atomicMax seg-max (0 encodes below all floats)
__device__ __forceinline__ unsigned enc_f(float f) {
    unsigned u = __float_as_uint(f);
    return (u & 0x80000000u) ? ~u : (u | 0x80000000u);
}
__device__ __forceinline__ float dec_f(unsigned e) {
    unsigned u = (e & 0x80000000u) ? (e & 0x7FFFFFFFu) : ~e;
    return __uint_as_float(u);
}
__device__ __forceinline__ u16 f2bf(float f) {  // RTNE fp32->bf16
    unsigned u = __float_as_uint(f);
    u += 0x7FFFu + ((u >> 16) & 1u);
    return (u16)(u >> 16);
}
__device__ __forceinline__ uint4 pack8(float4 a, float4 b) {
    union { u16 u[8]; uint4 v; } p;
    p.u[0]=f2bf(a.x); p.u[1]=f2bf(a.y); p.u[2]=f2bf(a.z); p.u[3]=f2bf(a.w);
    p.u[4]=f2bf(b.x); p.u[5]=f2bf(b.y); p.u[6]=f2bf(b.z); p.u[7]=f2bf(b.w);
    return p.v;
}

// async global->LDS, 16B per lane. LDS dest must be wave-uniform base (+lane*16 by HW).
__device__ __forceinline__ void gload16(const u16* g, u16* l) {
    __builtin_amdgcn_global_load_lds(
        (const __attribute__((address_space(1))) unsigned int*)(g),
        (__attribute__((address_space(3))) unsigned int*)(l), 16, 0, 0);
}

// ---- W [K][256] fp32 -> Wt [256][K] bf16 (transposed for B-frag b128 reads)
__global__ void wprep_kernel(const float* __restrict__ W, u16* __restrict__ Wt, int K) {
    int k = blockIdx.x, c = threadIdx.x;
    Wt[(size_t)c * K + k] = f2bf(W[(size_t)k * 256 + c]);
}

// ---- fp32 table -> bf16 table (8 elems/thread)
__global__ void tobf16_kernel(const float* __restrict__ in, u16* __restrict__ out, int n8) {
    int i = blockIdx.x * 256 + threadIdx.x;
    if (i < n8) {
        const float4* p = (const float4*)in + (size_t)2 * i;
        float4 a = p[0], b = p[1];
        ((uint4*)out)[i] = pack8(a, b);
    }
}

__global__ void hist_kernel(const int* __restrict__ arg_edge, unsigned* __restrict__ counts) {
    int i = blockIdx.x * 256 + threadIdx.x;
    if (i < A_CNT) atomicAdd(&counts[arg_edge[i]], 1u);
}

__global__ __launch_bounds__(1024) void scan_kernel(const unsigned* __restrict__ counts,
                                                    unsigned* __restrict__ cursor) {
    __shared__ unsigned sd[1024];
    const int tid = threadIdx.x;
    const int CH = (E_CNT + 1023) / 1024;  // 59
    const int base = tid * CH;
    unsigned s = 0;
    for (int i = 0; i < CH; ++i) { int idx = base + i; if (idx < E_CNT) s += counts[idx]; }
    sd[tid] = s; __syncthreads();
    for (int d = 1; d < 1024; d <<= 1) {
        unsigned v = (tid >= d) ? sd[tid - d] : 0u; __syncthreads();
        sd[tid] += v; __syncthreads();
    }
    unsigned run = sd[tid] - s;  // exclusive base
    for (int i = 0; i < CH; ++i) {
        int idx = base + i;
        if (idx < E_CNT) { cursor[idx] = run; run += counts[idx]; }
    }
}

__global__ void scatter_kernel(const int* __restrict__ arg_edge, unsigned* __restrict__ cursor,
                               unsigned* __restrict__ perm, unsigned* __restrict__ sorted_edge) {
    int i = blockIdx.x * 256 + threadIdx.x;
    if (i < A_CNT) {
        int e = arg_edge[i];
        unsigned pos = atomicAdd(&cursor[e], 1u);
        perm[pos] = (unsigned)i;
        sorted_edge[pos] = (unsigned)e;
    }
}

// ============================================================
// Type-message fold: only T_TYPES=512 distinct type rows exist (vs E=60k
// edge rows). Compute their messages once (scalar VALU, trivial FLOPs),
// enc-encode; einit broadcasts them as the seg-max INIT value per edge.
// Removes E rows from gemm1 (-19%) and 15.4M atomics, and the enc memset.
// Type row layout in X: [type(256) | zeros(128)] -> k in [0,256).
// ============================================================
__global__ void tmsg_kernel(const u16* __restrict__ types_bf, const u16* __restrict__ Wt1,
                            const float* __restrict__ b1, unsigned* __restrict__ tmsg_enc) {
    const int tt = blockIdx.x, c = threadIdx.x;
    const u16* xr = types_bf + (size_t)tt * H_DIM;
    const u16* wr = Wt1 + (size_t)c * K1;
    float acc = 0.f;
    for (int k = 0; k < H_DIM; k += 8) {
        v8s x = *(const v8s*)&xr[k];
        v8s w = *(const v8s*)&wr[k];
        #pragma unroll
        for (int u = 0; u < 8; ++u) {
            float xf = __uint_as_float((unsigned)(u16)x[u] << 16);
            float wf = __uint_as_float((unsigned)(u16)w[u] << 16);
            acc += xf * wf;
        }
    }
    float y = acc + b1[c];
    y = (y >= 0.f) ? y : NEG_SLOPE * y;
    tmsg_enc[(size_t)tt * H_DIM + c] = enc_f(y);
}

// enc[e][:] = tmsg_enc[type_idx[e]][:]  (uint4 per thread; replaces memset)
__global__ void einit_kernel(const int* __restrict__ type_idx,
                             const unsigned* __restrict__ tmsg_enc,
                             unsigned* __restrict__ enc) {
    size_t i = (size_t)blockIdx.x * 256 + threadIdx.x;   // uint4 units
    if (i < (size_t)E_CNT * (H_DIM / 4)) {
        int e  = (int)(i >> 6);
        int c4 = (int)(i & 63);
        int tt = type_idx[e];
        ((uint4*)enc)[i] = ((const uint4*)tmsg_enc)[(size_t)tt * 64 + c4];
    }
}

// ============================================================
// GEMM1: rows = sorted args only (type rows folded into enc init).
// X @ W1 + b1, leaky, run-compressed atomicMax seg-max into enc table.
// 128x128 tile, 256 thr. bf16 tables gathered via global_load_lds(16B),
// double-buffered LDS, counted vmcnt(4). launch_bounds (256,3): (256,5)
// forced VGPR<=102 -> acc spill -> 2x WRITE_SIZE (round-2 regression).
// ============================================================
__global__ __launch_bounds__(256, 3) void gemm1_kernel(
    const u16* __restrict__ nodes_bf, const int* __restrict__ arg_node_idx,
    const u16* __restrict__ names_bf, const int* __restrict__ arg_name_idx,
    const unsigned* __restrict__ perm, const unsigned* __restrict__ sorted_edge,
    const u16* __restrict__ Wt1, const float* __restrict__ b1,
    const u16* __restrict__ zbuf,
    unsigned* __restrict__ enc)
{
    __shared__ __align__(16) u16 sX[2 * LDSZ];
    __shared__ __align__(16) u16 sW[2 * LDSZ];
    const int t = threadIdx.x;
    const int lane = t & 63, wave = t >> 6;
    const int row0 = blockIdx.x * 128;
    const int col0 = blockIdx.y * 128;

    // staging geometry: call c stages LDS rows [c*64 + wave*16, +16); this lane
    // covers row rloc = c*64 + wave*16 + (lane>>2), 16B slot (lane&3).
    const int rsub = wave * 16 + (lane >> 2);
    const int slot = lane & 3;

    const u16* xs0[2]; const u16* xs1[2]; int valid[2];
    const u16* ws[2];
    u16* xdst[2]; u16* wdst[2];
    #pragma unroll
    for (int c = 0; c < 2; ++c) {
        const int rloc = c * 64 + rsub;
        const int ss = slot ^ ((rloc >> 1) & 3);   // inverse-swizzled SOURCE slot
        const int gr = row0 + rloc;
        if (gr < A_CNT) {
            int aid = (int)perm[gr];
            valid[c] = 1;
            xs0[c] = names_bf + (size_t)arg_name_idx[aid] * DA + ss * 8;
            xs1[c] = nodes_bf + (size_t)arg_node_idx[aid] * H_DIM + ss * 8 - DA;
        } else {
            valid[c] = 0; xs0[c] = zbuf; xs1[c] = zbuf;
        }
        ws[c]   = Wt1 + (size_t)(col0 + rloc) * K1 + ss * 8;
        xdst[c] = &sX[(c * 64 + wave * 16) * 32];   // wave-uniform
        wdst[c] = &sW[(c * 64 + wave * 16) * 32];
    }

    const int wr = (wave & 1) * 64, wc = (wave >> 1) * 64;
    const int lm = lane & 15, lq = lane >> 4;

    // read offsets (ushorts), fixed across k-steps; swizzled slot on read
    int xoff[4], woff[4];
    #pragma unroll
    for (int i = 0; i < 4; ++i) {
        int ra = wr + i * 16 + lm;
        xoff[i] = ra * 32 + (lq ^ ((ra >> 1) & 3)) * 8;
        int rb = wc + i * 16 + lm;
        woff[i] = rb * 32 + (lq ^ ((rb >> 1) & 3)) * 8;
    }

    v4f acc[4][4];
    #pragma unroll
    for (int i = 0; i < 4; ++i)
        #pragma unroll
        for (int j = 0; j < 4; ++j) acc[i][j] = (v4f)0.f;

    auto stage = [&](int buf, int kc) {   // exactly 4 vmem instructions / wave
        #pragma unroll
        for (int c = 0; c < 2; ++c) {
            const u16* xsrc = valid[c] ? (((kc < DA) ? xs0[c] : xs1[c]) + kc) : zbuf;
            gload16(xsrc, xdst[c] + buf * LDSZ);
            gload16(ws[c] + kc, wdst[c] + buf * LDSZ);
        }
    };

    const int nt = K1 / 32;   // 12
    stage(0, 0);
    for (int tt = 0; tt < nt; ++tt) {
        if (tt + 1 < nt) {
            stage((tt + 1) & 1, (tt + 1) * 32);
            asm volatile("s_waitcnt vmcnt(4)" ::: "memory");   // prev stage done, next in flight
        } else {
            asm volatile("s_waitcnt vmcnt(0)" ::: "memory");
        }
        __builtin_amdgcn_sched_barrier(0);
        __builtin_amdgcn_s_barrier();       // all waves: buf[tt&1] fully staged
        __builtin_amdgcn_sched_barrier(0);

        const u16* bx = &sX[(tt & 1) * LDSZ];
        const u16* bw = &sW[(tt & 1) * LDSZ];
        v8s af[4], bf[4];
        #pragma unroll
        for (int i = 0; i < 4; ++i) af[i] = *(const v8s*)&bx[xoff[i]];
        #pragma unroll
        for (int j = 0; j < 4; ++j) bf[j] = *(const v8s*)&bw[woff[j]];
        #pragma unroll
        for (int i = 0; i < 4; ++i)
            #pragma unroll
            for (int j = 0; j < 4; ++j)
                acc[i][j] = __builtin_amdgcn_mfma_f32_16x16x32_bf16(af[i], bf[j], acc[i][j], 0, 0, 0);

        __builtin_amdgcn_sched_barrier(0);
        __builtin_amdgcn_s_barrier();       // all reads of buf[tt&1] done before it is re-staged
    }

    float bb[4];
    #pragma unroll
    for (int j = 0; j < 4; ++j) bb[j] = b1[col0 + wc + j*16 + lm];

    #pragma unroll
    for (int i = 0; i < 4; ++i) {
        const int r0 = row0 + wr + i*16 + lq*4;
        unsigned seg[4];
        #pragma unroll
        for (int reg = 0; reg < 4; ++reg) {
            int g = r0 + reg;
            seg[reg] = (g < A_CNT) ? sorted_edge[g] : SENT;
        }
        #pragma unroll
        for (int j = 0; j < 4; ++j) {
            const int cj = col0 + wc + j*16 + lm;
            float v[4];
            #pragma unroll
            for (int reg = 0; reg < 4; ++reg) {
                float y = acc[i][j][reg] + bb[j];
                v[reg] = (y >= 0.f) ? y : NEG_SLOPE * y;
            }
            unsigned cs = seg[0]; float m = v[0];
            #pragma unroll
            for (int reg = 1; reg < 4; ++reg) {
                if (seg[reg] == cs) { m = fmaxf(m, v[reg]); }
                else {
                    if (cs != SENT) atomicMax(&enc[(size_t)cs * H_DIM + cj], enc_f(m));
                    cs = seg[reg]; m = v[reg];
                }
            }
            if (cs != SENT) atomicMax(&enc[(size_t)cs * H_DIM + cj], enc_f(m));
        }
    }
}

// decode enc(u32) -> fp32 in place (d_out edge slab) + bf16 copy for gemm2 gather (4/thread)
__global__ void decode_kernel(unsigned* __restrict__ enc, u16* __restrict__ es_bf) {
    size_t i = (size_t)blockIdx.x * 1024 + threadIdx.x;
    const size_t n4 = (size_t)E_CNT * H_DIM / 4;
    if (i < n4) {
        uint4 e = ((const uint4*)enc)[i];
        float4 f;
        f.x = dec_f(e.x); f.y = dec_f(e.y); f.z = dec_f(e.z); f.w = dec_f(e.w);
        ((float4*)enc)[i] = f;
        union { u16 u[4]; unsigned long long v; } p;
        p.u[0]=f2bf(f.x); p.u[1]=f2bf(f.y); p.u[2]=f2bf(f.z); p.u[3]=f2bf(f.w);
        ((unsigned long long*)es_bf)[i] = p.v;
    }
}

// ============================================================
// GEMM2: rows = args (original order), X = [es(256)|name(128)|node(256)] all bf16
// ============================================================
__global__ __launch_bounds__(256, 3) void gemm2_kernel(
    const u16* __restrict__ nodes_bf, const int* __restrict__ arg_node_idx,
    const u16* __restrict__ names_bf, const int* __restrict__ arg_name_idx,
    const int* __restrict__ arg_edge, const u16* __restrict__ es_bf,
    const u16* __restrict__ Wt2, const float* __restrict__ b2,
    const u16* __restrict__ zbuf,
    float* __restrict__ out)
{
    __shared__ __align__(16) u16 sX[2 * LDSZ];
    __shared__ __align__(16) u16 sW[2 * LDSZ];
    const int t = threadIdx.x;
    const int lane = t & 63, wave = t >> 6;
    const int row0 = blockIdx.x * 128;
    const int col0 = blockIdx.y * 128;

    const int rsub = wave * 16 + (lane >> 2);
    const int slot = lane & 3;

    const u16* pe[2]; const u16* pn[2]; const u16* pd[2]; int valid[2];
    const u16* ws[2];
    u16* xdst[2]; u16* wdst[2];
    #pragma unroll
    for (int c = 0; c < 2; ++c) {
        const int rloc = c * 64 + rsub;
        const int ss = slot ^ ((rloc >> 1) & 3);
        const int gr = row0 + rloc;
        if (gr < A_CNT) {
            valid[c] = 1;
            pe[c] = es_bf   + (size_t)arg_edge[gr]      * H_DIM + ss * 8;
            pn[c] = names_bf + (size_t)arg_name_idx[gr] * DA    + ss * 8 - H_DIM;
            pd[c] = nodes_bf + (size_t)arg_node_idx[gr] * H_DIM + ss * 8 - H_DIM - DA;
        } else {
            valid[c] = 0; pe[c] = zbuf; pn[c] = zbuf; pd[c] = zbuf;
        }
        ws[c]   = Wt2 + (size_t)(col0 + rloc) * K2 + ss * 8;
        xdst[c] = &sX[(c * 64 + wave * 16) * 32];
        wdst[c] = &sW[(c * 64 + wave * 16) * 32];
    }

    const int wr = (wave & 1) * 64, wc = (wave >> 1) * 64;
    const int lm = lane & 15, lq = lane >> 4;

    int xoff[4], woff[4];
    #pragma unroll
    for (int i = 0; i < 4; ++i) {
        int ra = wr + i * 16 + lm;
        xoff[i] = ra * 32 + (lq ^ ((ra >> 1) & 3)) * 8;
        int rb = wc + i * 16 + lm;
        woff[i] = rb * 32 + (lq ^ ((rb >> 1) & 3)) * 8;
    }

    v4f acc[4][4];
    #pragma unroll
    for (int i = 0; i < 4; ++i)
        #pragma unroll
        for (int j = 0; j < 4; ++j) acc[i][j] = (v4f)0.f;

    auto stage = [&](int buf, int kc) {   // exactly 4 vmem instructions / wave
        #pragma unroll
        for (int c = 0; c < 2; ++c) {
            const u16* xsrc;
            if (valid[c]) {
                const u16* p = (kc < H_DIM) ? pe[c] : ((kc < H_DIM + DA) ? pn[c] : pd[c]);
                xsrc = p + kc;
            } else xsrc = zbuf;
            gload16(xsrc, xdst[c] + buf * LDSZ);
            gload16(ws[c] + kc, wdst[c] + buf * LDSZ);
        }
    };

    const int nt = K2 / 32;   // 20
    stage(0, 0);
    for (int tt = 0; tt < nt; ++tt) {
        if (tt + 1 < nt) {
            stage((tt + 1) & 1, (tt + 1) * 32);
            asm volatile("s_waitcnt vmcnt(4)" ::: "memory");
        } else {
            asm volatile("s_waitcnt vmcnt(0)" ::: "memory");
        }
        __builtin_amdgcn_sched_barrier(0);
        __builtin_amdgcn_s_barrier();
        __builtin_amdgcn_sched_barrier(0);

        const u16* bx = &sX[(tt & 1) * LDSZ];
        const u16* bw = &sW[(tt & 1) * LDSZ];
        v8s af[4], bf[4];
        #pragma unroll
        for (int i = 0; i < 4; ++i) af[i] = *(const v8s*)&bx[xoff[i]];
        #pragma unroll
        for (int j = 0; j < 4; ++j) bf[j] = *(const v8s*)&bw[woff[j]];
        #pragma unroll
        for (int i = 0; i < 4; ++i)
            #pragma unroll
            for (int j = 0; j < 4; ++j)
                acc[i][j] = __builtin_amdgcn_mfma_f32_16x16x32_bf16(af[i], bf[j], acc[i][j], 0, 0, 0);

        __builtin_amdgcn_sched_barrier(0);
        __builtin_amdgcn_s_barrier();
    }

    float bb[4];
    #pragma unroll
    for (int j = 0; j < 4; ++j) bb[j] = b2[col0 + wc + j*16 + lm];

    #pragma unroll
    for (int i = 0; i < 4; ++i) {
        const int r0 = row0 + wr + i*16 + lq*4;
        #pragma unroll
        for (int reg = 0; reg < 4; ++reg) {
            const int g = r0 + reg;
            if (g < A_CNT) {
                #pragma unroll
                for (int j = 0; j < 4; ++j) {
                    float y = acc[i][j][reg] + bb[j];
                    y = (y >= 0.f) ? y : NEG_SLOPE * y;
                    out[(size_t)g * H_DIM + col0 + wc + j*16 + lm] = y;
                }
            }
        }
    }
}

extern "C" void kernel_launch(void* const* d_in, const int* in_sizes, int n_in,
                              void* d_out, int out_size, void* d_ws, size_t ws_size,
                              hipStream_t stream) {
    const float* nodes        = (const float*)d_in[0];
    const int*   arg_node_idx = (const int*)  d_in[1];
    const float* types        = (const float*)d_in[2];
    const int*   type_idx     = (const int*)  d_in[3];
    const float* names        = (const float*)d_in[4];
    const int*   arg_name_idx = (const int*)  d_in[5];
    const int*   arg_edge     = (const int*)  d_in[6];
    const float* W1           = (const float*)d_in[8];
    const float* b1           = (const float*)d_in[9];
    const float* W2           = (const float*)d_in[10];
    const float* b2           = (const float*)d_in[11];

    float* out_msg = (float*)d_out;                       // [A,256] fp32
    float* out_es  = out_msg + (size_t)A_CNT * H_DIM;     // [E,256] fp32
    unsigned* enc  = (unsigned*)out_es;                   // enc table lives in output slab

    char* ws = (char*)d_ws;
    size_t off = 0;
    auto alloc = [&](size_t bytes) -> void* {
        void* p = ws + off;
        off = (off + bytes + 255) & ~(size_t)255;
        return p;
    };
    u16* Wt1          = (u16*)alloc((size_t)256 * K1 * sizeof(u16));
    u16* Wt2          = (u16*)alloc((size_t)256 * K2 * sizeof(u16));
    u16* es_bf        = (u16*)alloc((size_t)E_CNT * H_DIM * sizeof(u16));
    u16* nodes_bf     = (u16*)alloc((size_t)N_NODES * H_DIM * sizeof(u16));
    u16* names_bf     = (u16*)alloc((size_t)M_NAMES * DA * sizeof(u16));
    u16* types_bf     = (u16*)alloc((size_t)T_TYPES * H_DIM * sizeof(u16));
    unsigned* tmsg_enc = (unsigned*)alloc((size_t)T_TYPES * H_DIM * sizeof(unsigned));
    u16* zbuf         = (u16*)alloc(256);
    unsigned* counts  = (unsigned*)alloc((size_t)E_CNT * sizeof(unsigned));
    unsigned* cursor  = (unsigned*)alloc((size_t)E_CNT * sizeof(unsigned));
    unsigned* perm    = (unsigned*)alloc((size_t)A_CNT * sizeof(unsigned));
    unsigned* sorted_edge = (unsigned*)alloc((size_t)A_CNT * sizeof(unsigned));

    hipMemsetAsync(counts, 0, (size_t)E_CNT * sizeof(unsigned), stream);
    hipMemsetAsync(zbuf, 0, 256, stream);

    wprep_kernel<<<K1, 256, 0, stream>>>(W1, Wt1, K1);
    wprep_kernel<<<K2, 256, 0, stream>>>(W2, Wt2, K2);
    {
        int n8 = N_NODES * H_DIM / 8;
        tobf16_kernel<<<(n8 + 255) / 256, 256, 0, stream>>>(nodes, nodes_bf, n8);
    }
    {
        int n8 = M_NAMES * DA / 8;
        tobf16_kernel<<<(n8 + 255) / 256, 256, 0, stream>>>(names, names_bf, n8);
    }
    {
        int n8 = T_TYPES * H_DIM / 8;
        tobf16_kernel<<<(n8 + 255) / 256, 256, 0, stream>>>(types, types_bf, n8);
    }
    hist_kernel<<<(A_CNT + 255) / 256, 256, 0, stream>>>(arg_edge, counts);
    scan_kernel<<<1, 1024, 0, stream>>>(counts, cursor);
    scatter_kernel<<<(A_CNT + 255) / 256, 256, 0, stream>>>(arg_edge, cursor, perm, sorted_edge);

    // type-message fold: 512 unique type messages -> enc init per edge
    tmsg_kernel<<<T_TYPES, 256, 0, stream>>>(types_bf, Wt1, b1, tmsg_enc);
    {
        size_t n4 = (size_t)E_CNT * (H_DIM / 4);
        einit_kernel<<<(unsigned)((n4 + 255) / 256), 256, 0, stream>>>(type_idx, tmsg_enc, enc);
    }

    dim3 g1((A_CNT + 127) / 128, 2);
    gemm1_kernel<<<g1, 256, 0, stream>>>(nodes_bf, arg_node_idx,
                                         names_bf, arg_name_idx, perm, sorted_edge,
                                         Wt1, b1, zbuf, enc);
    decode_kernel<<<((E_CNT * H_DIM / 4) + 1023) / 1024, 1024, 0, stream>>>(enc, es_bf);

    dim3 g2((A_CNT + 127) / 128, 2);
    gemm2_kernel<<<g2, 256, 0, stream>>>(nodes_bf, arg_node_idx, names_bf, arg_name_idx,
                                         arg_edge, es_bf, Wt2, b2, zbuf, out_msg);
}